// Round 5
// baseline (932.641 us; speedup 1.0000x reference)
//
#include <hip/hip_runtime.h>
#include <hip/hip_bf16.h>
#include <cstddef>

// Problem constants (fixed by the reference)
constexpr int T_ = 512;
constexpr int B_ = 8;
constexpr int H_ = 256;
constexpr int V_ = 32000;
constexpr int L_ = 3;
constexpr int M_ = T_ * B_;   // 4096 rows in all GEMMs

typedef __attribute__((ext_vector_type(8))) short short8;
typedef __attribute__((ext_vector_type(4))) float floatx4;

// fp32 -> bf16 round-to-nearest-even
__device__ __forceinline__ unsigned short f2bf(float f) {
    unsigned u = __float_as_uint(f);
    u += 0x7fffu + ((u >> 16) & 1u);
    return (unsigned short)(u >> 16);
}

// async global->LDS, 16B per lane; LDS dest = wave-uniform base + lane*16
__device__ __forceinline__ void gl_lds16(const void* g, void* l) {
    __builtin_amdgcn_global_load_lds((__attribute__((address_space(1))) void*)g,
                                     (__attribute__((address_space(3))) void*)l,
                                     16, 0, 0);
}

// ===========================================================================
// Session ledger (hard-won, do not regress):
//  - R7: NT stores on the 524MB C stream are LOAD-BEARING (+150us without).
//  - R8: grid.sync() ~50us each on MI355X -> no cooperative fusion.
//        By subtraction, out-GEMM ~140-235us vs ~85us write floor.
//  - R9: mega-fusion (64-block 96KB-LDS kernels) regresses +56us; dispatch
//        gaps are only ~4us -> never trade parallelism for launch count.
// ===========================================================================

// ---------------------------------------------------------------------------
// Prep kernel (one dispatch): weight transposes + embed (all independent).
//   blocks 0..95    : 6x [256][256] fp32 (k-major) -> [256][256] bf16 (WT)
//   blocks 96..2095 : Wout [256][32000] fp32 -> WoutT [32000][256] bf16
//   blocks 2096..3119: embed h_bf[t,b,:] = bf16(temb[tok]+pemb[t])
// ---------------------------------------------------------------------------
__global__ __launch_bounds__(256) void prep_kernel(
    const float* __restrict__ Wq, const float* __restrict__ Wfc,
    const float* __restrict__ Wout,
    const int* __restrict__ tokens, const float* __restrict__ temb,
    const float* __restrict__ pemb,
    unsigned short* __restrict__ WT, unsigned short* __restrict__ WoutT,
    unsigned short* __restrict__ h_bf)
{
    __shared__ float t[64][65];
    const int bx = blockIdx.x;

    if (bx >= 2096) {                    // ---- embed branch (block-uniform)
        const int idx = (bx - 2096) * 256 + threadIdx.x;   // 0..M*H/4-1
        const int h4 = idx & (H_ / 4 - 1);
        const int tb = idx >> 6;
        const int b  = tb & (B_ - 1);
        const int tt = tb >> 3;
        const int tok = tokens[tt * B_ + b];
        const float4 e = *(const float4*)&temb[(size_t)tok * H_ + h4 * 4];
        const float4 p = *(const float4*)&pemb[(size_t)tt * H_ + h4 * 4];
        ushort4 r;
        r.x = f2bf(e.x + p.x); r.y = f2bf(e.y + p.y);
        r.z = f2bf(e.z + p.z); r.w = f2bf(e.w + p.w);
        *(ushort4*)&h_bf[(size_t)idx * 4] = r;
        return;
    }

    const float* src; unsigned short* dst;
    int n0, k0, sstride;
    if (bx < 96) {                       // small: z = bx>>4, 4x4 tiles of 64
        const int z = bx >> 4, r = bx & 15;
        src = (z < 3) ? Wq + (size_t)z * H_ * H_
                      : Wfc + (size_t)(z - 3) * H_ * H_;
        dst = WT + (size_t)z * H_ * H_;
        n0 = (r & 3) * 64; k0 = (r >> 2) * 64;
        sstride = H_;
    } else {                             // Wout: (V/64=500) x (H/64=4)
        const int nb = bx - 96;
        src = Wout; dst = WoutT;
        n0 = (nb >> 2) * 64; k0 = (nb & 3) * 64;
        sstride = V_;
    }
    const int x = threadIdx.x & 63, y = threadIdx.x >> 6;
    #pragma unroll
    for (int i = 0; i < 16; ++i)
        t[y + 4 * i][x] = src[(size_t)(k0 + y + 4 * i) * sstride + n0 + x];
    __syncthreads();
    #pragma unroll
    for (int i = 0; i < 16; ++i)
        dst[(size_t)(n0 + y + 4 * i) * H_ + k0 + x] = f2bf(t[x][y + 4 * i]);
}

// ---------------------------------------------------------------------------
// Exact sequential leaky scan + spike, ONE kernel (R10).
// Grid (B_=8) x 256 thr: thread (b=blockIdx, h=tid) runs the reference
// recurrence mem = fmaf(beta, mem, cur[t]) for t=0..511 verbatim (bitwise
// the reference order -- no chunk approximation). Chain = 512 fmas ~0.9us;
// loads 1KB-coalesced per t-step, cur is L2-resident (written just before).
// Replaces the 2-kernel chunked scan: -1 dispatch/layer, no mloc buffer.
// ---------------------------------------------------------------------------
__global__ __launch_bounds__(256) void scan_seq_kernel(
    const float* __restrict__ cur, const float* __restrict__ beta_l,
    unsigned short* __restrict__ spk)
{
    const int b = blockIdx.x, h = threadIdx.x;
    const float bt = beta_l[h];
    const float* p = cur + (size_t)b * H_ + h;
    unsigned short* q = spk + (size_t)b * H_ + h;
    constexpr int TS = B_ * H_;          // 2048
    float mem = 0.0f;
    #pragma unroll 8
    for (int t = 0; t < T_; ++t) {
        mem = fmaf(bt, mem, p[(size_t)t * TS]);
        q[(size_t)t * TS] = (mem > 1.0f) ? (unsigned short)0x3F80u
                                         : (unsigned short)0u;
    }
}

// ===========================================================================
// XOR-swizzled LDS staging (all MFMA GEMMs): chunk = 16 B = 8 bf16 k-octet.
//   BK=64 tiles: slot = row*8 + (oct ^ (row & 7))        (layer GEMM)
//   BK=32 tiles: slot = row*4 + (oct ^ ((row>>1) & 3))   (out GEMM)
// Fragment ds_read_b128 stays at free 2-way bank aliasing (m136); gl_lds
// groups of 64 slots stay line-coalesced.
// ===========================================================================

// ---------------------------------------------------------------------------
// Layer GEMM: [M,256] = A[M,256]bf16 @ Bt[256,256]^T + bias, optional ReLU,
// output fp32 (for scan) or bf16 (activations). 64x64 tile, grid (64,4) =
// 256 blocks (full machine). 4 waves 2x2 over (32m x 32n). Proven R6 path.
// ---------------------------------------------------------------------------
template <int RELU, int OUT_BF16>
__global__ __launch_bounds__(256) void gemm_mfma_layer(
    const unsigned short* __restrict__ A,    // [M][256]
    const unsigned short* __restrict__ Bt,   // [256][256]
    const float* __restrict__ bias,          // [256]
    float* __restrict__ Cf, unsigned short* __restrict__ Cb)
{
    constexpr int K = H_, N = H_;
    __shared__ __align__(16) short lA[512][8];   // 64 rows x 8 octets
    __shared__ __align__(16) short lB[512][8];   // 64 rows

    const int tid = threadIdx.x;
    const int lane = tid & 63, wave = tid >> 6;
    const int wm = wave >> 1, wn = wave & 1;     // wave-tile 32m x 32n
    const int l15 = lane & 15, quad = lane >> 4;
    const int m0 = blockIdx.x * 64;
    const int n0 = blockIdx.y * 64;

    floatx4 acc[2][2] = {};

    for (int k0 = 0; k0 < K; k0 += 64) {
        #pragma unroll
        for (int j = 0; j < 2; ++j) {
            const int base = (wave * 2 + j) * 64;
            const int s = base + lane;
            const int row = s >> 3;
            const int oct = (s & 7) ^ (row & 7);
            gl_lds16(A + (size_t)(m0 + row) * K + k0 + oct * 8, &lA[base][0]);
        }
        #pragma unroll
        for (int j = 0; j < 2; ++j) {
            const int base = (wave * 2 + j) * 64;
            const int s = base + lane;
            const int row = s >> 3;
            const int oct = (s & 7) ^ (row & 7);
            gl_lds16(Bt + (size_t)(n0 + row) * K + k0 + oct * 8, &lB[base][0]);
        }
        __syncthreads();

        #pragma unroll
        for (int t = 0; t < 2; ++t) {
            short8 af[2], bf[2];
            #pragma unroll
            for (int f = 0; f < 2; ++f) {
                const int ra = wm * 32 + f * 16 + l15;
                af[f] = *(const short8*)&lA[ra * 8 + ((4 * t + quad) ^ (ra & 7))][0];
            }
            #pragma unroll
            for (int g = 0; g < 2; ++g) {
                const int rb = wn * 32 + g * 16 + l15;
                bf[g] = *(const short8*)&lB[rb * 8 + ((4 * t + quad) ^ (rb & 7))][0];
            }
            #pragma unroll
            for (int f = 0; f < 2; ++f)
                #pragma unroll
                for (int g = 0; g < 2; ++g)
                    acc[f][g] = __builtin_amdgcn_mfma_f32_16x16x32_bf16(
                        af[f], bf[g], acc[f][g], 0, 0, 0);
        }
        __syncthreads();
    }

    #pragma unroll
    for (int g = 0; g < 2; ++g) {
        const int col = n0 + wn * 32 + g * 16 + l15;
        const float bv = bias[col];
        #pragma unroll
        for (int f = 0; f < 2; ++f) {
            const int rbase = m0 + wm * 32 + f * 16 + quad * 4;
            #pragma unroll
            for (int r = 0; r < 4; ++r) {
                float v = acc[f][g][r] + bv;
                if (RELU) v = fmaxf(v, 0.0f);
                if (OUT_BF16)
                    Cb[(size_t)(rbase + r) * N + col] = f2bf(v);
                else
                    Cf[(size_t)(rbase + r) * N + col] = v;
            }
        }
    }
}

// ---------------------------------------------------------------------------
// Final projection: C[M,V] = A[M,256]bf16 @ WoutT[V,256]^T + bias, fp32 out.
// BK=32 double-buffered 2-phase K-pipeline; epilogue = per-wave LDS scratch
// -> full-line (4 rows x 256 B) NON-TEMPORAL stores (R7: do not remove NT).
// R10: grid order swapped to x = n (fast, 250), y = m (16). Co-resident
// ~512 blocks now cover rows m0..m0+511 x ALL n -> each occupancy round
// writes a CONTIGUOUS ~64MB region of C (DRAM page/burst locality for the
// NT stream), instead of 512-B slices scattered over the full 524MB.
// ---------------------------------------------------------------------------
__global__ __launch_bounds__(256, 2) void gemm_mfma_out(
    const unsigned short* __restrict__ A,    // [M][256] bf16
    const unsigned short* __restrict__ Bt,   // [V][256] bf16
    const float* __restrict__ bias,          // [V]
    float* __restrict__ C)
{
    constexpr int K = H_, N = V_;
    __shared__ __align__(16) short lA[2][1024][8];  // 2 x 16 KiB
    __shared__ __align__(16) short lB[2][512][8];   // 2 x  8 KiB

    const int tid = threadIdx.x;
    const int lane = tid & 63, wave = tid >> 6;
    const int wm = wave >> 1, wn = wave & 1;     // wave-tile: 128m x 64n
    const int l15 = lane & 15, quad = lane >> 4;
    const int n0 = blockIdx.x * 128;             // x = n (fast): write locality
    const int m0 = blockIdx.y * 256;

    floatx4 acc[8][4] = {};

    auto stage = [&](int buf, int ks) {
        const int k0 = ks * 32;
        #pragma unroll
        for (int j = 0; j < 4; ++j) {            // A: 1024 slots
            const int base = (wave * 4 + j) * 64;
            const int s = base + lane;
            const int row = s >> 2;
            const int oct = (s & 3) ^ ((row >> 1) & 3);
            gl_lds16(A + (size_t)(m0 + row) * K + k0 + oct * 8, &lA[buf][base][0]);
        }
        #pragma unroll
        for (int j = 0; j < 2; ++j) {            // B: 512 slots
            const int base = (wave * 2 + j) * 64;
            const int s = base + lane;
            const int row = s >> 2;
            const int oct = (s & 3) ^ ((row >> 1) & 3);
            gl_lds16(Bt + (size_t)(n0 + row) * K + k0 + oct * 8, &lB[buf][base][0]);
        }
    };

    stage(0, 0);
    __syncthreads();                              // buf0 staged (full drain)

    for (int ks = 0; ks < 8; ++ks) {
        const int cur = ks & 1;
        if (ks < 7) stage(cur ^ 1, ks + 1);       // prefetch next slice first
        short8 af[8], bf[4];
        #pragma unroll
        for (int f = 0; f < 8; ++f) {
            const int ra = wm * 128 + f * 16 + l15;
            af[f] = *(const short8*)&lA[cur][ra * 4 + (quad ^ ((ra >> 1) & 3))][0];
        }
        #pragma unroll
        for (int g = 0; g < 4; ++g) {
            const int rb = wn * 64 + g * 16 + l15;
            bf[g] = *(const short8*)&lB[cur][rb * 4 + (quad ^ ((rb >> 1) & 3))][0];
        }
        #pragma unroll
        for (int f = 0; f < 8; ++f)
            #pragma unroll
            for (int g = 0; g < 4; ++g)
                acc[f][g] = __builtin_amdgcn_mfma_f32_16x16x32_bf16(
                    af[f], bf[g], acc[f][g], 0, 0, 0);
        __syncthreads();
    }

    // ---- epilogue via per-wave LDS scratch -> full-line NT stores ----
    // D layout per frag: col(n) = l15, row(m) = quad*4 + r (m89/m91-verified).
    float* scr = (float*)&lA[0][0][0] + (size_t)wave * 1088;   // 16 x 68 fp32
    float bvv[4];
    #pragma unroll
    for (int g = 0; g < 4; ++g)
        bvv[g] = bias[n0 + wn * 64 + g * 16 + l15];

    #pragma unroll
    for (int f = 0; f < 8; ++f) {
        #pragma unroll
        for (int g = 0; g < 4; ++g)
            #pragma unroll
            for (int r = 0; r < 4; ++r)
                scr[(quad * 4 + r) * 68 + g * 16 + l15] = acc[f][g][r] + bvv[g];
        asm volatile("s_waitcnt lgkmcnt(0)" ::: "memory");
        #pragma unroll
        for (int rr = 0; rr < 4; ++rr) {
            const int ml = rr * 4 + quad;
            const floatx4 v = *(const floatx4*)&scr[ml * 68 + l15 * 4];
            const size_t m = (size_t)(m0 + wm * 128 + f * 16 + ml);
            __builtin_nontemporal_store(
                v, (floatx4*)&C[m * (size_t)N + n0 + wn * 64 + l15 * 4]);
        }
        asm volatile("s_waitcnt lgkmcnt(0)" ::: "memory");  // reads landed
    }
}

// ---------------------------------------------------------------------------
extern "C" void kernel_launch(void* const* d_in, const int* in_sizes, int n_in,
                              void* d_out, int out_size, void* d_ws, size_t ws_size,
                              hipStream_t stream)
{
    const int*   tokens = (const int*)  d_in[0];
    const float* temb   = (const float*)d_in[1];
    const float* pemb   = (const float*)d_in[2];
    const float* Wq     = (const float*)d_in[3];
    const float* bq     = (const float*)d_in[4];
    const float* beta   = (const float*)d_in[5];
    const float* Wfc    = (const float*)d_in[6];
    const float* bfc    = (const float*)d_in[7];
    const float* Wout   = (const float*)d_in[8];
    const float* bout   = (const float*)d_in[9];
    float* out = (float*)d_out;

    // Workspace layout (16B-aligned): h_bf 2MB | spk 2MB | WT 0.75MB |
    // WoutT 16MB | cur 4MB
    unsigned short* h_bf  = (unsigned short*)d_ws;
    unsigned short* spk   = h_bf + (size_t)M_ * H_;
    unsigned short* WT    = spk + (size_t)M_ * H_;          // 6 x [256][256]
    unsigned short* WoutT = WT + (size_t)2 * L_ * H_ * H_;
    float*          cur   = (float*)(WoutT + (size_t)V_ * H_);

    // 1) transposes + embed in one dispatch
    prep_kernel<<<96 + (V_ / 64) * (H_ / 64) + (M_ * H_ / 4) / 256,
                  256, 0, stream>>>(
        Wq, Wfc, Wout, tokens, temb, pemb, WT, WoutT, h_bf);

    // 2) layers: qproj (fp32) -> exact sequential scan+spike -> fc (bf16)
    for (int l = 0; l < L_; ++l) {
        const unsigned short* WqT  = WT + (size_t)l * H_ * H_;
        const unsigned short* WfcT = WT + (size_t)(L_ + l) * H_ * H_;
        gemm_mfma_layer<0, 0><<<dim3(M_ / 64, H_ / 64), 256, 0, stream>>>(
            h_bf, WqT, bq + (size_t)l * H_, cur, nullptr);
        scan_seq_kernel<<<B_, 256, 0, stream>>>(
            cur, beta + (size_t)l * H_, spk);
        gemm_mfma_layer<1, 1><<<dim3(M_ / 64, H_ / 64), 256, 0, stream>>>(
            spk, WfcT, bfc + (size_t)l * H_, nullptr, h_bf);
    }

    // 3) output projection: (4096 x 256) @ (256 x 32000) + bout
    gemm_mfma_out<<<dim3(V_ / 128, M_ / 256), 256, 0, stream>>>(
        h_bf, WoutT, bout, out);
}

// Round 6
// 787.851 us; speedup vs baseline: 1.1838x; 1.1838x over previous
//
#include <hip/hip_runtime.h>
#include <hip/hip_bf16.h>
#include <cstddef>

// Problem constants (fixed by the reference)
constexpr int T_ = 512;
constexpr int B_ = 8;
constexpr int H_ = 256;
constexpr int V_ = 32000;
constexpr int L_ = 3;
constexpr int M_ = T_ * B_;   // 4096 rows in all GEMMs

typedef __attribute__((ext_vector_type(8))) short short8;
typedef __attribute__((ext_vector_type(4))) float floatx4;

// fp32 -> bf16 round-to-nearest-even
__device__ __forceinline__ unsigned short f2bf(float f) {
    unsigned u = __float_as_uint(f);
    u += 0x7fffu + ((u >> 16) & 1u);
    return (unsigned short)(u >> 16);
}

// async global->LDS, 16B per lane; LDS dest = wave-uniform base + lane*16
__device__ __forceinline__ void gl_lds16(const void* g, void* l) {
    __builtin_amdgcn_global_load_lds((__attribute__((address_space(1))) void*)g,
                                     (__attribute__((address_space(3))) void*)l,
                                     16, 0, 0);
}

// ===========================================================================
// Session ledger (hard-won, do not regress):
//  - R7:  NT stores on the 524MB C stream are LOAD-BEARING (+150us without).
//  - R8:  grid.sync() ~50us each on MI355X -> no cooperative fusion.
//  - R9:  mega-fusion (64-block 96KB-LDS kernels) regresses +56us; dispatch
//         gaps are only ~4us -> never trade parallelism for launch count.
//  - R10: out-GEMM grid MUST be x = m (fast): co-dispatched blocks share the
//         64KB Bt panel; x=n-fast re-streams 16MB WoutT per m-round (+165us).
//         Scans need >=128 blocks; an 8-block exact scan starved the chip.
//  - Proven-safe micro-wins: R7 fused prefix scan (bitwise exact, 128 blk),
//         R10 prep merge (embed inside transpose dispatch).
// ===========================================================================

// ---------------------------------------------------------------------------
// Prep kernel (one dispatch): weight transposes + embed (all independent).
//   blocks 0..95    : 6x [256][256] fp32 (k-major) -> [256][256] bf16 (WT)
//   blocks 96..2095 : Wout [256][32000] fp32 -> WoutT [32000][256] bf16
//   blocks 2096..3119: embed h_bf[t,b,:] = bf16(temb[tok]+pemb[t])
// ---------------------------------------------------------------------------
__global__ __launch_bounds__(256) void prep_kernel(
    const float* __restrict__ Wq, const float* __restrict__ Wfc,
    const float* __restrict__ Wout,
    const int* __restrict__ tokens, const float* __restrict__ temb,
    const float* __restrict__ pemb,
    unsigned short* __restrict__ WT, unsigned short* __restrict__ WoutT,
    unsigned short* __restrict__ h_bf)
{
    __shared__ float t[64][65];
    const int bx = blockIdx.x;

    if (bx >= 2096) {                    // ---- embed branch (block-uniform)
        const int idx = (bx - 2096) * 256 + threadIdx.x;   // 0..M*H/4-1
        const int h4 = idx & (H_ / 4 - 1);
        const int tb = idx >> 6;
        const int b  = tb & (B_ - 1);
        const int tt = tb >> 3;
        const int tok = tokens[tt * B_ + b];
        const float4 e = *(const float4*)&temb[(size_t)tok * H_ + h4 * 4];
        const float4 p = *(const float4*)&pemb[(size_t)tt * H_ + h4 * 4];
        ushort4 r;
        r.x = f2bf(e.x + p.x); r.y = f2bf(e.y + p.y);
        r.z = f2bf(e.z + p.z); r.w = f2bf(e.w + p.w);
        *(ushort4*)&h_bf[(size_t)idx * 4] = r;
        return;
    }

    const float* src; unsigned short* dst;
    int n0, k0, sstride;
    if (bx < 96) {                       // small: z = bx>>4, 4x4 tiles of 64
        const int z = bx >> 4, r = bx & 15;
        src = (z < 3) ? Wq + (size_t)z * H_ * H_
                      : Wfc + (size_t)(z - 3) * H_ * H_;
        dst = WT + (size_t)z * H_ * H_;
        n0 = (r & 3) * 64; k0 = (r >> 2) * 64;
        sstride = H_;
    } else {                             // Wout: (V/64=500) x (H/64=4)
        const int nb = bx - 96;
        src = Wout; dst = WoutT;
        n0 = (nb >> 2) * 64; k0 = (nb & 3) * 64;
        sstride = V_;
    }
    const int x = threadIdx.x & 63, y = threadIdx.x >> 6;
    #pragma unroll
    for (int i = 0; i < 16; ++i)
        t[y + 4 * i][x] = src[(size_t)(k0 + y + 4 * i) * sstride + n0 + x];
    __syncthreads();
    #pragma unroll
    for (int i = 0; i < 16; ++i)
        dst[(size_t)(n0 + y + 4 * i) * H_ + k0 + x] = f2bf(t[x][y + 4 * i]);
}

// ===========================================================================
// Fused leaky scan + spike (R7-proven, absmax 0.0): block (c,b) re-runs the
// EXACT sequential recurrence mem = fmaf(beta, mem, cur[t]) from t=0 through
// its chunk's end (redundant prefix, <=512 dependent FMAs; loads off the
// dependent chain; cur L2/L3-resident, ~31MB redundant reads total), then
// stores spikes for its own 32-t chunk. 128 blocks (R10 lesson: >=128).
// Bitwise-identical to the reference scan.
// ===========================================================================
constexpr int CH_ = 32;
constexpr int NT_ = T_ / CH_;          // 16 chunks
constexpr int TS_ = B_ * H_;           // 2048: t-stride in [T][B][H]

__global__ __launch_bounds__(256) void scan_spike_kernel(
    const float* __restrict__ cur, const float* __restrict__ beta_l,
    unsigned short* __restrict__ spk)
{
    const int c = blockIdx.x, b = blockIdx.y, h = threadIdx.x;
    const float bt = beta_l[h];
    const float* p = cur + (size_t)b * H_ + h;
    float mem = 0.0f;
    const int pre = c * CH_;
    #pragma unroll 8
    for (int t = 0; t < pre; ++t)
        mem = fmaf(bt, mem, p[(size_t)t * TS_]);
    const float* pc = p + (size_t)pre * TS_;
    unsigned short* q = spk + ((size_t)pre * B_ + b) * H_ + h;
    #pragma unroll
    for (int tt = 0; tt < CH_; ++tt) {
        mem = fmaf(bt, mem, pc[(size_t)tt * TS_]);
        q[(size_t)tt * TS_] = (mem > 1.0f) ? (unsigned short)0x3F80u
                                           : (unsigned short)0u;
    }
}

// ===========================================================================
// XOR-swizzled LDS staging (all MFMA GEMMs): chunk = 16 B = 8 bf16 k-octet.
//   BK=64 tiles: slot = row*8 + (oct ^ (row & 7))        (layer GEMM)
//   BK=32 tiles: slot = row*4 + (oct ^ ((row>>1) & 3))   (out GEMM)
// Fragment ds_read_b128 stays at free 2-way bank aliasing (m136); gl_lds
// groups of 64 slots stay line-coalesced.
// ===========================================================================

// ---------------------------------------------------------------------------
// Layer GEMM: [M,256] = A[M,256]bf16 @ Bt[256,256]^T + bias, optional ReLU,
// output fp32 (for scan) or bf16 (activations). 64x64 tile, grid (64,4) =
// 256 blocks (full machine). 4 waves 2x2 over (32m x 32n). Proven R6 path.
// ---------------------------------------------------------------------------
template <int RELU, int OUT_BF16>
__global__ __launch_bounds__(256) void gemm_mfma_layer(
    const unsigned short* __restrict__ A,    // [M][256]
    const unsigned short* __restrict__ Bt,   // [256][256]
    const float* __restrict__ bias,          // [256]
    float* __restrict__ Cf, unsigned short* __restrict__ Cb)
{
    constexpr int K = H_, N = H_;
    __shared__ __align__(16) short lA[512][8];   // 64 rows x 8 octets
    __shared__ __align__(16) short lB[512][8];   // 64 rows

    const int tid = threadIdx.x;
    const int lane = tid & 63, wave = tid >> 6;
    const int wm = wave >> 1, wn = wave & 1;     // wave-tile 32m x 32n
    const int l15 = lane & 15, quad = lane >> 4;
    const int m0 = blockIdx.x * 64;
    const int n0 = blockIdx.y * 64;

    floatx4 acc[2][2] = {};

    for (int k0 = 0; k0 < K; k0 += 64) {
        #pragma unroll
        for (int j = 0; j < 2; ++j) {
            const int base = (wave * 2 + j) * 64;
            const int s = base + lane;
            const int row = s >> 3;
            const int oct = (s & 7) ^ (row & 7);
            gl_lds16(A + (size_t)(m0 + row) * K + k0 + oct * 8, &lA[base][0]);
        }
        #pragma unroll
        for (int j = 0; j < 2; ++j) {
            const int base = (wave * 2 + j) * 64;
            const int s = base + lane;
            const int row = s >> 3;
            const int oct = (s & 7) ^ (row & 7);
            gl_lds16(Bt + (size_t)(n0 + row) * K + k0 + oct * 8, &lB[base][0]);
        }
        __syncthreads();

        #pragma unroll
        for (int t = 0; t < 2; ++t) {
            short8 af[2], bf[2];
            #pragma unroll
            for (int f = 0; f < 2; ++f) {
                const int ra = wm * 32 + f * 16 + l15;
                af[f] = *(const short8*)&lA[ra * 8 + ((4 * t + quad) ^ (ra & 7))][0];
            }
            #pragma unroll
            for (int g = 0; g < 2; ++g) {
                const int rb = wn * 32 + g * 16 + l15;
                bf[g] = *(const short8*)&lB[rb * 8 + ((4 * t + quad) ^ (rb & 7))][0];
            }
            #pragma unroll
            for (int f = 0; f < 2; ++f)
                #pragma unroll
                for (int g = 0; g < 2; ++g)
                    acc[f][g] = __builtin_amdgcn_mfma_f32_16x16x32_bf16(
                        af[f], bf[g], acc[f][g], 0, 0, 0);
        }
        __syncthreads();
    }

    #pragma unroll
    for (int g = 0; g < 2; ++g) {
        const int col = n0 + wn * 32 + g * 16 + l15;
        const float bv = bias[col];
        #pragma unroll
        for (int f = 0; f < 2; ++f) {
            const int rbase = m0 + wm * 32 + f * 16 + quad * 4;
            #pragma unroll
            for (int r = 0; r < 4; ++r) {
                float v = acc[f][g][r] + bv;
                if (RELU) v = fmaxf(v, 0.0f);
                if (OUT_BF16)
                    Cb[(size_t)(rbase + r) * N + col] = f2bf(v);
                else
                    Cf[(size_t)(rbase + r) * N + col] = v;
            }
        }
    }
}

// ---------------------------------------------------------------------------
// Final projection: C[M,V] = A[M,256]bf16 @ WoutT[V,256]^T + bias, fp32 out.
// R11: retiled 256x128 -> 128x128 (BK=32 dbuf 2-phase unchanged, x=m fast
// unchanged, NT epilogue unchanged). VGPR ~200 -> ~110, LDS 48 -> 32 KB,
// __launch_bounds__(256,3): 3 blocks/CU instead of 2, so the per-K-step
// barrier vmcnt-drain and the epilogue store phase overlap across 3 resident
// blocks. Per-output k-accumulation order unchanged (ascending 32-k steps)
// -> bitwise-same C. 4 waves 2x2 over (64m x 64n); grid (M/128=32, V/128).
// ---------------------------------------------------------------------------
__global__ __launch_bounds__(256, 3) void gemm_mfma_out(
    const unsigned short* __restrict__ A,    // [M][256] bf16
    const unsigned short* __restrict__ Bt,   // [V][256] bf16
    const float* __restrict__ bias,          // [V]
    float* __restrict__ C)
{
    constexpr int K = H_, N = V_;
    __shared__ __align__(16) short lA[2][512][8];   // 2 x 8 KiB: 128 rows x 4 oct
    __shared__ __align__(16) short lB[2][512][8];   // 2 x 8 KiB

    const int tid = threadIdx.x;
    const int lane = tid & 63, wave = tid >> 6;
    const int wm = wave >> 1, wn = wave & 1;     // wave-tile: 64m x 64n
    const int l15 = lane & 15, quad = lane >> 4;
    const int m0 = blockIdx.x * 128;             // x = m (fast): R10 lesson
    const int n0 = blockIdx.y * 128;

    floatx4 acc[4][4] = {};

    auto stage = [&](int buf, int ks) {
        const int k0 = ks * 32;
        #pragma unroll
        for (int j = 0; j < 2; ++j) {            // A: 512 slots
            const int base = (wave * 2 + j) * 64;
            const int s = base + lane;
            const int row = s >> 2;
            const int oct = (s & 3) ^ ((row >> 1) & 3);
            gl_lds16(A + (size_t)(m0 + row) * K + k0 + oct * 8, &lA[buf][base][0]);
        }
        #pragma unroll
        for (int j = 0; j < 2; ++j) {            // B: 512 slots
            const int base = (wave * 2 + j) * 64;
            const int s = base + lane;
            const int row = s >> 2;
            const int oct = (s & 3) ^ ((row >> 1) & 3);
            gl_lds16(Bt + (size_t)(n0 + row) * K + k0 + oct * 8, &lB[buf][base][0]);
        }
    };

    stage(0, 0);
    __syncthreads();                              // buf0 staged (full drain)

    for (int ks = 0; ks < 8; ++ks) {
        const int cur = ks & 1;
        if (ks < 7) stage(cur ^ 1, ks + 1);       // prefetch next slice first
        short8 af[4], bf[4];
        #pragma unroll
        for (int f = 0; f < 4; ++f) {
            const int ra = wm * 64 + f * 16 + l15;
            af[f] = *(const short8*)&lA[cur][ra * 4 + (quad ^ ((ra >> 1) & 3))][0];
        }
        #pragma unroll
        for (int g = 0; g < 4; ++g) {
            const int rb = wn * 64 + g * 16 + l15;
            bf[g] = *(const short8*)&lB[cur][rb * 4 + (quad ^ ((rb >> 1) & 3))][0];
        }
        #pragma unroll
        for (int f = 0; f < 4; ++f)
            #pragma unroll
            for (int g = 0; g < 4; ++g)
                acc[f][g] = __builtin_amdgcn_mfma_f32_16x16x32_bf16(
                    af[f], bf[g], acc[f][g], 0, 0, 0);
        __syncthreads();
    }

    // ---- epilogue via per-wave LDS scratch -> full-line NT stores ----
    // D layout per frag: col(n) = l15, row(m) = quad*4 + r (m89/m91-verified).
    // Scratch wave-private (4352 B each, 17.4 KB total <= 32 KB LDS);
    // per-wave lgkmcnt(0) orders cross-lane LDS write->read.
    float* scr = (float*)&lA[0][0][0] + (size_t)wave * 1088;   // 16 x 68 fp32
    float bvv[4];
    #pragma unroll
    for (int g = 0; g < 4; ++g)
        bvv[g] = bias[n0 + wn * 64 + g * 16 + l15];

    #pragma unroll
    for (int f = 0; f < 4; ++f) {
        #pragma unroll
        for (int g = 0; g < 4; ++g)
            #pragma unroll
            for (int r = 0; r < 4; ++r)
                scr[(quad * 4 + r) * 68 + g * 16 + l15] = acc[f][g][r] + bvv[g];
        asm volatile("s_waitcnt lgkmcnt(0)" ::: "memory");
        #pragma unroll
        for (int rr = 0; rr < 4; ++rr) {
            const int ml = rr * 4 + quad;
            const floatx4 v = *(const floatx4*)&scr[ml * 68 + l15 * 4];
            const size_t m = (size_t)(m0 + wm * 64 + f * 16 + ml);
            __builtin_nontemporal_store(
                v, (floatx4*)&C[m * (size_t)N + n0 + wn * 64 + l15 * 4]);
        }
        asm volatile("s_waitcnt lgkmcnt(0)" ::: "memory");  // reads landed
    }
}

// ---------------------------------------------------------------------------
extern "C" void kernel_launch(void* const* d_in, const int* in_sizes, int n_in,
                              void* d_out, int out_size, void* d_ws, size_t ws_size,
                              hipStream_t stream)
{
    const int*   tokens = (const int*)  d_in[0];
    const float* temb   = (const float*)d_in[1];
    const float* pemb   = (const float*)d_in[2];
    const float* Wq     = (const float*)d_in[3];
    const float* bq     = (const float*)d_in[4];
    const float* beta   = (const float*)d_in[5];
    const float* Wfc    = (const float*)d_in[6];
    const float* bfc    = (const float*)d_in[7];
    const float* Wout   = (const float*)d_in[8];
    const float* bout   = (const float*)d_in[9];
    float* out = (float*)d_out;

    // Workspace layout (16B-aligned): h_bf 2MB | spk 2MB | WT 0.75MB |
    // WoutT 16MB | cur 4MB
    unsigned short* h_bf  = (unsigned short*)d_ws;
    unsigned short* spk   = h_bf + (size_t)M_ * H_;
    unsigned short* WT    = spk + (size_t)M_ * H_;          // 6 x [256][256]
    unsigned short* WoutT = WT + (size_t)2 * L_ * H_ * H_;
    float*          cur   = (float*)(WoutT + (size_t)V_ * H_);

    // 1) transposes + embed in one dispatch
    prep_kernel<<<96 + (V_ / 64) * (H_ / 64) + (M_ * H_ / 4) / 256,
                  256, 0, stream>>>(
        Wq, Wfc, Wout, tokens, temb, pemb, WT, WoutT, h_bf);

    // 2) layers: qproj (fp32) -> fused prefix scan+spike -> fc (bf16)
    for (int l = 0; l < L_; ++l) {
        const unsigned short* WqT  = WT + (size_t)l * H_ * H_;
        const unsigned short* WfcT = WT + (size_t)(L_ + l) * H_ * H_;
        gemm_mfma_layer<0, 0><<<dim3(M_ / 64, H_ / 64), 256, 0, stream>>>(
            h_bf, WqT, bq + (size_t)l * H_, cur, nullptr);
        scan_spike_kernel<<<dim3(NT_, B_), 256, 0, stream>>>(
            cur, beta + (size_t)l * H_, spk);
        gemm_mfma_layer<1, 1><<<dim3(M_ / 64, H_ / 64), 256, 0, stream>>>(
            spk, WfcT, bfc + (size_t)l * H_, nullptr, h_bf);
    }

    // 3) output projection: (4096 x 256) @ (256 x 32000) + bout
    gemm_mfma_out<<<dim3(M_ / 128, V_ / 128), 256, 0, stream>>>(
        h_bf, WoutT, bout, out);
}

// Round 8
// 653.425 us; speedup vs baseline: 1.4273x; 1.2057x over previous
//
#include <hip/hip_runtime.h>
#include <hip/hip_bf16.h>
#include <cstddef>

// Problem constants (fixed by the reference)
constexpr int T_ = 512;
constexpr int B_ = 8;
constexpr int H_ = 256;
constexpr int V_ = 32000;
constexpr int L_ = 3;
constexpr int M_ = T_ * B_;   // 4096 rows in all GEMMs

typedef __attribute__((ext_vector_type(8))) short short8;
typedef __attribute__((ext_vector_type(4))) float floatx4;

// fp32 -> bf16 round-to-nearest-even
__device__ __forceinline__ unsigned short f2bf(float f) {
    unsigned u = __float_as_uint(f);
    u += 0x7fffu + ((u >> 16) & 1u);
    return (unsigned short)(u >> 16);
}

// async global->LDS, 16B per lane; LDS dest = wave-uniform base + lane*16
__device__ __forceinline__ void gl_lds16(const void* g, void* l) {
    __builtin_amdgcn_global_load_lds((__attribute__((address_space(1))) void*)g,
                                     (__attribute__((address_space(3))) void*)l,
                                     16, 0, 0);
}

// ===========================================================================
// Session ledger (hard-won, do not regress):
//  - R7:  NT stores on the 524MB C stream are LOAD-BEARING (+150us without).
//  - R8:  grid.sync() ~50us each on MI355X -> no cooperative fusion.
//  - R9:  mega-fusion (64-block 96KB-LDS kernels) regresses +56us; dispatch
//         gaps are only ~4us -> never trade parallelism for launch count.
//  - R10: out-GEMM grid MUST be x = m (fast): co-dispatched blocks share the
//         Bt panel; x=n-fast re-streams 16MB WoutT per m-round (+165us).
//         Scans need >=128 blocks; an 8-block exact scan starved the chip.
//  - R11: out-GEMM 128x128 @ (256,3) retile regressed ~+95 (VGPR cap 128 ->
//         spills; less MFMA per barrier). KEEP 256m x 128n @ (256,2).
//  - BK=64 single-buffer vs BK=32 dbuf in out-GEMM measured IDENTICAL
//         (657 vs 661) -> the K-loop is not the bottleneck; write-bound.
//  This round: R0-exact (657.2us measured) + prep merge ONLY (-2 gaps).
//  (R7 attempt of this exact source failed on container acquisition —
//   resubmitted unchanged.)
// ===========================================================================

// ---------------------------------------------------------------------------
// Prep kernel (one dispatch): weight transposes + embed (all independent).
//   blocks 0..95    : 6x [256][256] fp32 (k-major) -> [256][256] bf16 (WT)
//   blocks 96..2095 : Wout [256][32000] fp32 -> WoutT [32000][256] bf16
//   blocks 2096..3119: embed h_bf[t,b,:] = bf16(temb[tok]+pemb[t])
// ---------------------------------------------------------------------------
__global__ __launch_bounds__(256) void prep_kernel(
    const float* __restrict__ Wq, const float* __restrict__ Wfc,
    const float* __restrict__ Wout,
    const int* __restrict__ tokens, const float* __restrict__ temb,
    const float* __restrict__ pemb,
    unsigned short* __restrict__ WT, unsigned short* __restrict__ WoutT,
    unsigned short* __restrict__ h_bf)
{
    __shared__ float t[64][65];
    const int bx = blockIdx.x;

    if (bx >= 2096) {                    // ---- embed branch (block-uniform)
        const int idx = (bx - 2096) * 256 + threadIdx.x;   // 0..M*H/4-1
        const int h4 = idx & (H_ / 4 - 1);
        const int tb = idx >> 6;
        const int b  = tb & (B_ - 1);
        const int tt = tb >> 3;
        const int tok = tokens[tt * B_ + b];
        const float4 e = *(const float4*)&temb[(size_t)tok * H_ + h4 * 4];
        const float4 p = *(const float4*)&pemb[(size_t)tt * H_ + h4 * 4];
        ushort4 r;
        r.x = f2bf(e.x + p.x); r.y = f2bf(e.y + p.y);
        r.z = f2bf(e.z + p.z); r.w = f2bf(e.w + p.w);
        *(ushort4*)&h_bf[(size_t)idx * 4] = r;
        return;
    }

    const float* src; unsigned short* dst;
    int n0, k0, sstride;
    if (bx < 96) {                       // small: z = bx>>4, 4x4 tiles of 64
        const int z = bx >> 4, r = bx & 15;
        src = (z < 3) ? Wq + (size_t)z * H_ * H_
                      : Wfc + (size_t)(z - 3) * H_ * H_;
        dst = WT + (size_t)z * H_ * H_;
        n0 = (r & 3) * 64; k0 = (r >> 2) * 64;
        sstride = H_;
    } else {                             // Wout: (V/64=500) x (H/64=4)
        const int nb = bx - 96;
        src = Wout; dst = WoutT;
        n0 = (nb >> 2) * 64; k0 = (nb & 3) * 64;
        sstride = V_;
    }
    const int x = threadIdx.x & 63, y = threadIdx.x >> 6;
    #pragma unroll
    for (int i = 0; i < 16; ++i)
        t[y + 4 * i][x] = src[(size_t)(k0 + y + 4 * i) * sstride + n0 + x];
    __syncthreads();
    #pragma unroll
    for (int i = 0; i < 16; ++i)
        dst[(size_t)(n0 + y + 4 * i) * H_ + k0 + x] = f2bf(t[x][y + 4 * i]);
}

// ===========================================================================
// Parallel chunked leaky scan (linear recurrence; chunk-local + carry apply).
// Spike margin ~0.9 vs the ~1e-7 reordering delta -> no spike flips.
// (R0-exact; absmax 0.0 measured.)
// ===========================================================================
constexpr int CH_ = 32;
constexpr int NT_ = T_ / CH_;          // 16 chunks
constexpr int TS_ = B_ * H_;           // 2048: t-stride in [T][B][H]

__global__ __launch_bounds__(256) void scan_local_kernel(
    const float* __restrict__ cur, const float* __restrict__ beta_l,
    float* __restrict__ mloc)
{
    const int c = blockIdx.x, b = blockIdx.y, h = threadIdx.x;
    const float bt = beta_l[h];
    const size_t off = ((size_t)(c * CH_) * B_ + b) * H_ + h;
    const float* p = cur + off;
    float* q = mloc + off;
    float mem = 0.0f;
    #pragma unroll
    for (int tt = 0; tt < CH_; ++tt) {
        mem = fmaf(bt, mem, p[(size_t)tt * TS_]);
        q[(size_t)tt * TS_] = mem;
    }
}

__global__ __launch_bounds__(256) void scan_apply_kernel(
    const float* __restrict__ mloc, const float* __restrict__ beta_l,
    unsigned short* __restrict__ spk)
{
    const int c = blockIdx.x, b = blockIdx.y, h = threadIdx.x;
    const float bt = beta_l[h];
    float b32 = bt;
    #pragma unroll
    for (int i = 0; i < 5; ++i) b32 *= b32;        // beta^32 (CH_=32)
    float carry = 0.0f;
    for (int j = 0; j < c; ++j)
        carry = fmaf(b32, carry,
                     mloc[((size_t)(j * CH_ + CH_ - 1) * B_ + b) * H_ + h]);
    const size_t off = ((size_t)(c * CH_) * B_ + b) * H_ + h;
    const float* p = mloc + off;
    unsigned short* q = spk + off;
    float pw = bt;                                  // beta^(tt+1)
    #pragma unroll
    for (int tt = 0; tt < CH_; ++tt) {
        const float mem = fmaf(pw, carry, p[(size_t)tt * TS_]);
        pw *= bt;
        q[(size_t)tt * TS_] = (mem > 1.0f) ? (unsigned short)0x3F80u
                                           : (unsigned short)0u;
    }
}

// ===========================================================================
// XOR-swizzled LDS staging scheme (all MFMA GEMMs):
//   chunk = 16 B = 8 bf16 = one k-octet. Row of a BK=64 tile = 8 octets.
//   Slot for (row, oct):  s = row*8 + (oct ^ (row & 7)),  LDS byte addr s*16.
//   global_load_lds groups of 64 slots = 8 rows x 8 permuted octets
//   = 8 x 128 B coalesced line reads; fragment ds_read_b128 spreads uniformly
//   over all 32 banks (2-way max aliasing = free per m136).
// ===========================================================================

// ---------------------------------------------------------------------------
// Final projection: C[M,V] = A[M,256]bf16 @ WoutT[V,256]^T + bias, fp32 out.
// R0-exact (657.2us config): 256m x 128n block, 4 waves 2x2, wave-tile
// 128x64, BK=64 single-buffered K-loop. Epilogue: each wave routes its
// C-tile through a private LDS scratch (16x68 fp32) 16 rows at a time, then
// emits NT float4 stores in FULL 256-B-contiguous row segments. NT bypasses
// L2 so the 524 MB C stream cannot evict A/Wt (R7: load-bearing, +150us
// without).
// ---------------------------------------------------------------------------
__global__ __launch_bounds__(256, 2) void gemm_mfma_out(
    const unsigned short* __restrict__ A,    // [M][256] bf16
    const unsigned short* __restrict__ Bt,   // [V][256] bf16
    const float* __restrict__ bias,          // [V]
    float* __restrict__ C)
{
    constexpr int K = H_, N = V_;
    __shared__ __align__(16) short lA[2048][8];   // 32 KiB: 256 rows x 8 octets
    __shared__ __align__(16) short lB[1024][8];   // 16 KiB: 128 rows

    const int tid = threadIdx.x;
    const int lane = tid & 63, wave = tid >> 6;
    const int wm = wave >> 1, wn = wave & 1;     // wave-tile: 128m x 64n
    const int l15 = lane & 15, quad = lane >> 4;
    const int m0 = blockIdx.x * 256;             // x = m (fast): 16 blocks/n-tile
    const int n0 = blockIdx.y * 128;

    floatx4 acc[8][4] = {};

    for (int k0 = 0; k0 < K; k0 += 64) {
        // stage A: 256 rows x 8 octets = 2048 slots
        #pragma unroll
        for (int j = 0; j < 8; ++j) {
            const int base = (wave * 8 + j) * 64;
            const int s = base + lane;
            const int row = s >> 3;
            const int oct = (s & 7) ^ (row & 7);
            gl_lds16(A + (size_t)(m0 + row) * K + k0 + oct * 8, &lA[base][0]);
        }
        // stage B: 128 rows = 1024 slots
        #pragma unroll
        for (int j = 0; j < 4; ++j) {
            const int base = (wave * 4 + j) * 64;
            const int s = base + lane;
            const int row = s >> 3;
            const int oct = (s & 7) ^ (row & 7);
            gl_lds16(Bt + (size_t)(n0 + row) * K + k0 + oct * 8, &lB[base][0]);
        }
        __syncthreads();

        #pragma unroll
        for (int t = 0; t < 2; ++t) {
            short8 af[8], bf[4];
            #pragma unroll
            for (int f = 0; f < 8; ++f) {
                const int ra = wm * 128 + f * 16 + l15;
                af[f] = *(const short8*)&lA[ra * 8 + ((4 * t + quad) ^ (ra & 7))][0];
            }
            #pragma unroll
            for (int g = 0; g < 4; ++g) {
                const int rb = wn * 64 + g * 16 + l15;
                bf[g] = *(const short8*)&lB[rb * 8 + ((4 * t + quad) ^ (rb & 7))][0];
            }
            #pragma unroll
            for (int f = 0; f < 8; ++f)
                #pragma unroll
                for (int g = 0; g < 4; ++g)
                    acc[f][g] = __builtin_amdgcn_mfma_f32_16x16x32_bf16(
                        af[f], bf[g], acc[f][g], 0, 0, 0);
        }
        __syncthreads();
    }

    // ---- epilogue via per-wave LDS scratch -> full-line NT stores ----
    // D layout per frag: col(n) = l15, row(m) = quad*4 + r (m89/m91-verified).
    float* scr = (float*)&lA[0][0] + (size_t)wave * 1088;   // 16 x 68 fp32
    float bvv[4];
    #pragma unroll
    for (int g = 0; g < 4; ++g)
        bvv[g] = bias[n0 + wn * 64 + g * 16 + l15];

    #pragma unroll
    for (int f = 0; f < 8; ++f) {
        // scatter this 16-row chunk (m-local x 64 n-local) into scratch
        #pragma unroll
        for (int g = 0; g < 4; ++g)
            #pragma unroll
            for (int r = 0; r < 4; ++r)
                scr[(quad * 4 + r) * 68 + g * 16 + l15] = acc[f][g][r] + bvv[g];
        __syncthreads();   // uniform: orders LDS writes before reads
        // gather row-major: 4 instrs x (4 rows x 256 B contiguous)
        #pragma unroll
        for (int rr = 0; rr < 4; ++rr) {
            const int ml = rr * 4 + quad;
            const floatx4 v = *(const floatx4*)&scr[ml * 68 + l15 * 4];
            const size_t m = (size_t)(m0 + wm * 128 + f * 16 + ml);
            __builtin_nontemporal_store(
                v, (floatx4*)&C[m * (size_t)N + n0 + wn * 64 + l15 * 4]);
        }
        __syncthreads();   // reads done before next chunk overwrites
    }
}

// ---------------------------------------------------------------------------
// Layer GEMM: [M,256] = A[M,256]bf16 @ Bt[256,256]^T + bias, optional ReLU,
// output fp32 (for scan) or bf16 (activations). 128x64 tile, BK=64, 4 waves
// 2x2 over (64m x 32n). (R0-exact; ~3 us each.)
// ---------------------------------------------------------------------------
template <int RELU, int OUT_BF16>
__global__ __launch_bounds__(256) void gemm_mfma_layer(
    const unsigned short* __restrict__ A,    // [M][256]
    const unsigned short* __restrict__ Bt,   // [256][256]
    const float* __restrict__ bias,          // [256]
    float* __restrict__ Cf, unsigned short* __restrict__ Cb)
{
    constexpr int K = H_, N = H_;
    __shared__ __align__(16) short lA[1024][8];   // 128 rows
    __shared__ __align__(16) short lB[512][8];    // 64 rows

    const int tid = threadIdx.x;
    const int lane = tid & 63, wave = tid >> 6;
    const int wm = wave >> 1, wn = wave & 1;
    const int l15 = lane & 15, quad = lane >> 4;
    const int m0 = blockIdx.x * 128;
    const int n0 = blockIdx.y * 64;

    floatx4 acc[4][2] = {};

    for (int k0 = 0; k0 < K; k0 += 64) {
        #pragma unroll
        for (int j = 0; j < 4; ++j) {
            const int base = (wave * 4 + j) * 64;
            const int s = base + lane;
            const int row = s >> 3;
            const int oct = (s & 7) ^ (row & 7);
            gl_lds16(A + (size_t)(m0 + row) * K + k0 + oct * 8, &lA[base][0]);
        }
        #pragma unroll
        for (int j = 0; j < 2; ++j) {
            const int base = (wave * 2 + j) * 64;
            const int s = base + lane;
            const int row = s >> 3;
            const int oct = (s & 7) ^ (row & 7);
            gl_lds16(Bt + (size_t)(n0 + row) * K + k0 + oct * 8, &lB[base][0]);
        }
        __syncthreads();

        #pragma unroll
        for (int t = 0; t < 2; ++t) {
            short8 af[4], bf[2];
            #pragma unroll
            for (int f = 0; f < 4; ++f) {
                const int ra = wm * 64 + f * 16 + l15;
                af[f] = *(const short8*)&lA[ra * 8 + ((4 * t + quad) ^ (ra & 7))][0];
            }
            #pragma unroll
            for (int f = 0; f < 2; ++f) {
                const int rb = wn * 32 + f * 16 + l15;
                bf[f] = *(const short8*)&lB[rb * 8 + ((4 * t + quad) ^ (rb & 7))][0];
            }
            #pragma unroll
            for (int i = 0; i < 4; ++i)
                #pragma unroll
                for (int j2 = 0; j2 < 2; ++j2)
                    acc[i][j2] = __builtin_amdgcn_mfma_f32_16x16x32_bf16(
                        af[i], bf[j2], acc[i][j2], 0, 0, 0);
        }
        __syncthreads();
    }

    #pragma unroll
    for (int j2 = 0; j2 < 2; ++j2) {
        const int col = n0 + wn * 32 + j2 * 16 + l15;
        const float bv = bias[col];
        #pragma unroll
        for (int i = 0; i < 4; ++i) {
            const int rbase = m0 + wm * 64 + i * 16 + quad * 4;
            #pragma unroll
            for (int r = 0; r < 4; ++r) {
                float v = acc[i][j2][r] + bv;
                if (RELU) v = fmaxf(v, 0.0f);
                if (OUT_BF16)
                    Cb[(size_t)(rbase + r) * N + col] = f2bf(v);
                else
                    Cf[(size_t)(rbase + r) * N + col] = v;
            }
        }
    }
}

// ---------------------------------------------------------------------------
extern "C" void kernel_launch(void* const* d_in, const int* in_sizes, int n_in,
                              void* d_out, int out_size, void* d_ws, size_t ws_size,
                              hipStream_t stream)
{
    const int*   tokens = (const int*)  d_in[0];
    const float* temb   = (const float*)d_in[1];
    const float* pemb   = (const float*)d_in[2];
    const float* Wq     = (const float*)d_in[3];
    const float* bq     = (const float*)d_in[4];
    const float* beta   = (const float*)d_in[5];
    const float* Wfc    = (const float*)d_in[6];
    const float* bfc    = (const float*)d_in[7];
    const float* Wout   = (const float*)d_in[8];
    const float* bout   = (const float*)d_in[9];
    float* out = (float*)d_out;

    // Workspace layout (all 16B-aligned): h_bf 2MB | spk 2MB | WT 0.75MB |
    // WoutT 16MB | cur 4MB | mloc 4MB
    unsigned short* h_bf  = (unsigned short*)d_ws;
    unsigned short* spk   = h_bf + (size_t)M_ * H_;
    unsigned short* WT    = spk + (size_t)M_ * H_;          // 6 x [256][256]
    unsigned short* WoutT = WT + (size_t)2 * L_ * H_ * H_;
    float*          cur   = (float*)(WoutT + (size_t)V_ * H_);
    float*          mloc  = cur + (size_t)M_ * H_;

    // 1) transposes + embed in one dispatch (-2 launch gaps vs R0)
    prep_kernel<<<96 + (V_ / 64) * (H_ / 64) + (M_ * H_ / 4) / 256,
                  256, 0, stream>>>(
        Wq, Wfc, Wout, tokens, temb, pemb, WT, WoutT, h_bf);

    // 2) layers: qproj (fp32 out) -> parallel scan/spike (bf16 out) -> fc
    for (int l = 0; l < L_; ++l) {
        const unsigned short* WqT  = WT + (size_t)l * H_ * H_;
        const unsigned short* WfcT = WT + (size_t)(L_ + l) * H_ * H_;
        gemm_mfma_layer<0, 0><<<dim3(M_ / 128, H_ / 64), 256, 0, stream>>>(
            h_bf, WqT, bq + (size_t)l * H_, cur, nullptr);
        scan_local_kernel<<<dim3(NT_, B_), 256, 0, stream>>>(
            cur, beta + (size_t)l * H_, mloc);
        scan_apply_kernel<<<dim3(NT_, B_), 256, 0, stream>>>(
            mloc, beta + (size_t)l * H_, spk);
        gemm_mfma_layer<1, 1><<<dim3(M_ / 128, H_ / 64), 256, 0, stream>>>(
            spk, WfcT, bfc + (size_t)l * H_, nullptr, h_bf);
    }

    // 3) output projection: (4096 x 256) @ (256 x 32000) + bout
    gemm_mfma_out<<<dim3(M_ / 256, V_ / 128), 256, 0, stream>>>(
        h_bf, WoutT, bout, out);
}